// Round 9
// baseline (215.225 us; speedup 1.0000x reference)
//
#include <hip/hip_runtime.h>

#define T_LEN 2048

typedef float f4 __attribute__((ext_vector_type(4)));

// --- one timestep: hybrid DPP + ds_bpermute gather ---------------------------
// h_new[j] = relu( xi_t[j] + sum_k W_hh[j,k]*h[k] ), xi_t = x_t*wih + bias.
// 8 k-terms via fused v_fmac_f32_dpp (VALU pipe, ~5cyc each), 7 k-terms via
// ds_bpermute_b32 (LDS-crossbar pipe, runs concurrent with the DPP block) +
// plain fmaf on return. bpermute issues first (right after h is ready) so its
// latency overlaps the DPP issue stream.
__device__ __forceinline__ void step(float& h, float& xi, float xsn,
                                     const float (&w)[9], const float (&wb)[7],
                                     const int (&ab)[7], float wih, float bias) {
  // Issue the 7 crossbar gathers ASAP (independent of the asm block below).
  int hb = __float_as_int(h);
  float g0 = __int_as_float(__builtin_amdgcn_ds_bpermute(ab[0], hb));
  float g1 = __int_as_float(__builtin_amdgcn_ds_bpermute(ab[1], hb));
  float g2 = __int_as_float(__builtin_amdgcn_ds_bpermute(ab[2], hb));
  float g3 = __int_as_float(__builtin_amdgcn_ds_bpermute(ab[3], hb));
  float g4 = __int_as_float(__builtin_amdgcn_ds_bpermute(ab[4], hb));
  float g5 = __int_as_float(__builtin_amdgcn_ds_bpermute(ab[5], hb));
  float g6 = __int_as_float(__builtin_amdgcn_ds_bpermute(ab[6], hb));

  // Fused-DPP partial (s=1..8) + xi filler + plain w0 term. First DPP read of
  // h is the 3rd instruction -> hazard spacing satisfied inside the block.
  float a0, a1, a2, xon;
  asm("v_fma_f32 %[xon], %[xsn], %[wih], %[bs]\n\t"
      "v_fma_f32 %[a0], %[h], %[w0], %[xi]\n\t"
      "v_mul_f32_dpp  %[a1], %[h], %[w1] row_ror:1 row_mask:0xf bank_mask:0xf\n\t"
      "v_mul_f32_dpp  %[a2], %[h], %[w2] row_ror:2 row_mask:0xf bank_mask:0xf\n\t"
      "v_fmac_f32_dpp %[a0], %[h], %[w3] row_ror:3 row_mask:0xf bank_mask:0xf\n\t"
      "v_fmac_f32_dpp %[a1], %[h], %[w4] row_ror:4 row_mask:0xf bank_mask:0xf\n\t"
      "v_fmac_f32_dpp %[a2], %[h], %[w5] row_ror:5 row_mask:0xf bank_mask:0xf\n\t"
      "v_fmac_f32_dpp %[a0], %[h], %[w6] row_ror:6 row_mask:0xf bank_mask:0xf\n\t"
      "v_fmac_f32_dpp %[a1], %[h], %[w7] row_ror:7 row_mask:0xf bank_mask:0xf\n\t"
      "v_fmac_f32_dpp %[a2], %[h], %[w8] row_ror:8 row_mask:0xf bank_mask:0xf"
      : [xon] "=&v"(xon), [a0] "=&v"(a0), [a1] "=&v"(a1), [a2] "=&v"(a2)
      : [h] "v"(h), [xi] "v"(xi), [xsn] "v"(xsn), [wih] "v"(wih), [bs] "v"(bias),
        [w0] "v"(w[0]), [w1] "v"(w[1]), [w2] "v"(w[2]), [w3] "v"(w[3]),
        [w4] "v"(w[4]), [w5] "v"(w[5]), [w6] "v"(w[6]), [w7] "v"(w[7]),
        [w8] "v"(w[8]));

  // Crossbar terms fold into the three chains as results arrive.
  a0 = fmaf(g0, wb[0], a0);
  a1 = fmaf(g1, wb[1], a1);
  a2 = fmaf(g2, wb[2], a2);
  a0 = fmaf(g3, wb[3], a0);
  a1 = fmaf(g4, wb[4], a1);
  a2 = fmaf(g5, wb[5], a2);
  a0 = fmaf(g6, wb[6], a0);
  h  = fmaxf(a0 + (a1 + a2), 0.0f);
  xi = xon;
}

#define S1(XN) step(h, xi, (XN), w, wb, ab, wih, bias);
#define HALF_A                                                              \
  S1(A0.y) S1(A0.z) S1(A0.w) S1(A1.x) S1(A1.y) S1(A1.z) S1(A1.w) S1(A2.x)  \
  S1(A2.y) S1(A2.z) S1(A2.w) S1(A3.x) S1(A3.y) S1(A3.z) S1(A3.w) S1(B0.x)
#define HALF_B                                                              \
  S1(B0.y) S1(B0.z) S1(B0.w) S1(B1.x) S1(B1.y) S1(B1.z) S1(B1.w) S1(B2.x)  \
  S1(B2.y) S1(B2.z) S1(B2.w) S1(B3.x) S1(B3.y) S1(B3.z) S1(B3.w) S1(A0.x)

// --- kernel ------------------------------------------------------------------
__global__ __launch_bounds__(256) void rnn_relu_kernel(
    const float* __restrict__ x, const float* __restrict__ W_ih,
    const float* __restrict__ b_ih, const float* __restrict__ W_hh,
    const float* __restrict__ b_hh, const float* __restrict__ W_fc,
    const float* __restrict__ b_fc, float* __restrict__ out) {
  const int tid  = threadIdx.x;
  const int lane = tid & 63;
  const int j    = tid & 15;                       // h index owned by this lane
  const int b    = blockIdx.x * 16 + (tid >> 4);   // batch per 16-lane row

  // Probe row_ror:1 direction (ctrl 0x121 == asm row_ror:1), R1/R2-proven.
  int pr = __builtin_amdgcn_update_dpp(0, j, 0x121, 0xF, 0xF, true);
  const bool plus = (pr == ((j + 1) & 15));

  // DPP terms s=0..8: w[s] = W_hh[j][(j + dir*s) & 15].
  float w[9];
#pragma unroll
  for (int s = 0; s < 9; ++s) {
    int k = (j + (plus ? s : (16 - s) & 15)) & 15;
    w[s] = W_hh[j * 16 + k];
  }
  // bpermute terms: the complement k-offsets (dir*9 .. dir*15). Explicit lane
  // addressing -> no direction ambiguity beyond matching the complement set.
  float wb[7];
  int   ab[7];
  const int rowbase = lane & 0x30;
#pragma unroll
  for (int o = 0; o < 7; ++o) {
    int k = (j + (plus ? (9 + o) : (7 - o))) & 15;
    wb[o] = W_hh[j * 16 + k];
    ab[o] = (rowbase | k) << 2;
  }
  const float wih  = W_ih[j];
  const float bias = b_ih[j] + b_hh[j];

  // R6-proven load pipeline: A/B double-buffered f4 quads, loads issued a
  // full 16 steps before first use; no copies, no branch in body.
  const f4* __restrict__ xr = (const f4*)(x + (size_t)b * T_LEN);

  float h = 0.0f;
  f4 A0 = xr[0], A1 = xr[1], A2 = xr[2], A3 = xr[3];
  f4 B0, B1, B2, B3;
  float xi = fmaf(A0.x, wih, bias);        // xi for step 0
  const f4* p = xr + 4;                    // chunk t0+16 (B source)

#pragma unroll 1
  for (int t0 = 0; t0 < T_LEN; t0 += 32) {
    B0 = p[0]; B1 = p[1]; B2 = p[2]; B3 = p[3];     // load chunk t0+16
    HALF_A                                           // steps t0 .. t0+15
    const f4* pa = (t0 + 32 < T_LEN) ? (p + 4) : xr; // wrap on final iter
    A0 = pa[0]; A1 = pa[1]; A2 = pa[2]; A3 = pa[3];  // load chunk t0+32
    HALF_B                                           // steps t0+16 .. t0+31
    p += 8;
  }

  // Epilogue: out[b, c] = sum_j h[j] * W_fc[c, j] + b_fc[c]  (R2-proven)
  float p0 = h * W_fc[j];
  float p1 = h * W_fc[16 + j];
  p0 += __int_as_float(__builtin_amdgcn_ds_swizzle(__float_as_int(p0), 0x041F));
  p1 += __int_as_float(__builtin_amdgcn_ds_swizzle(__float_as_int(p1), 0x041F));
  p0 += __int_as_float(__builtin_amdgcn_ds_swizzle(__float_as_int(p0), 0x081F));
  p1 += __int_as_float(__builtin_amdgcn_ds_swizzle(__float_as_int(p1), 0x081F));
  p0 += __int_as_float(__builtin_amdgcn_ds_swizzle(__float_as_int(p0), 0x101F));
  p1 += __int_as_float(__builtin_amdgcn_ds_swizzle(__float_as_int(p1), 0x101F));
  p0 += __int_as_float(__builtin_amdgcn_ds_swizzle(__float_as_int(p0), 0x201F));
  p1 += __int_as_float(__builtin_amdgcn_ds_swizzle(__float_as_int(p1), 0x201F));

  if (j == 0) {
    out[b * 2 + 0] = p0 + b_fc[0];
    out[b * 2 + 1] = p1 + b_fc[1];
  }
}

// --- launch ------------------------------------------------------------------
extern "C" void kernel_launch(void* const* d_in, const int* in_sizes, int n_in,
                              void* d_out, int out_size, void* d_ws, size_t ws_size,
                              hipStream_t stream) {
  const float* x    = (const float*)d_in[0];
  const float* W_ih = (const float*)d_in[1];
  const float* b_ih = (const float*)d_in[2];
  const float* W_hh = (const float*)d_in[3];
  const float* b_hh = (const float*)d_in[4];
  const float* W_fc = (const float*)d_in[5];
  const float* b_fc = (const float*)d_in[6];
  float* out = (float*)d_out;

  const int B = 4096;
  dim3 grid(B / 16);   // 256 blocks: 4 batches/wave, 1024 waves = 1/SIMD
  dim3 block(256);
  hipLaunchKernelGGL(rnn_relu_kernel, grid, block, 0, stream,
                     x, W_ih, b_ih, W_hh, b_hh, W_fc, b_fc, out);
}

// Round 10
// 99.300 us; speedup vs baseline: 2.1674x; 2.1674x over previous
//
#include <hip/hip_runtime.h>

#define T_LEN 2048

typedef float f4 __attribute__((ext_vector_type(4)));

// --- one timestep ------------------------------------------------------------
// h_new[j] = relu( xi_t[j] + sum_k W_hh[j,k]*h[k] ), xi_t = x_t*wih + bias.
// 22 insts, FIVE accumulator chains with exact spacing-5 (≈10 cyc) between
// writes to the same chain -- discriminator between DPP-issue-limited (wash)
// and DPP-latency-limited (win) models. First DPP read of h is the 3rd inst
// after the previous step's max write (hazard-safe). Tail adds ordered so
// each add's operands are >=3 insts old.
__device__ __forceinline__ void step(float& h, float& xi, float xsn,
                                     const float (&w)[16], float wih, float bias) {
  float a0, a1, a2, a3, a4, xon;
  asm("v_fma_f32 %[xon], %[xsn], %[wih], %[bs]\n\t"    // 1: next xi (indep)
      "v_fma_f32 %[a0], %[h], %[w0], %[xi]\n\t"        // 2: plain h read
      "v_mul_f32_dpp  %[a1], %[h], %[w1]  row_ror:1  row_mask:0xf bank_mask:0xf\n\t"  // 3
      "v_mul_f32_dpp  %[a2], %[h], %[w2]  row_ror:2  row_mask:0xf bank_mask:0xf\n\t"  // 4
      "v_mul_f32_dpp  %[a3], %[h], %[w3]  row_ror:3  row_mask:0xf bank_mask:0xf\n\t"  // 5
      "v_mul_f32_dpp  %[a4], %[h], %[w4]  row_ror:4  row_mask:0xf bank_mask:0xf\n\t"  // 6
      "v_fmac_f32_dpp %[a0], %[h], %[w5]  row_ror:5  row_mask:0xf bank_mask:0xf\n\t"  // 7  (a0: 2->7)
      "v_fmac_f32_dpp %[a1], %[h], %[w6]  row_ror:6  row_mask:0xf bank_mask:0xf\n\t"  // 8  (a1: 3->8)
      "v_fmac_f32_dpp %[a2], %[h], %[w7]  row_ror:7  row_mask:0xf bank_mask:0xf\n\t"  // 9
      "v_fmac_f32_dpp %[a3], %[h], %[w8]  row_ror:8  row_mask:0xf bank_mask:0xf\n\t"  // 10
      "v_fmac_f32_dpp %[a4], %[h], %[w9]  row_ror:9  row_mask:0xf bank_mask:0xf\n\t"  // 11
      "v_fmac_f32_dpp %[a0], %[h], %[w10] row_ror:10 row_mask:0xf bank_mask:0xf\n\t"  // 12 (a0: 7->12)
      "v_fmac_f32_dpp %[a1], %[h], %[w11] row_ror:11 row_mask:0xf bank_mask:0xf\n\t"  // 13
      "v_fmac_f32_dpp %[a2], %[h], %[w12] row_ror:12 row_mask:0xf bank_mask:0xf\n\t"  // 14
      "v_fmac_f32_dpp %[a3], %[h], %[w13] row_ror:13 row_mask:0xf bank_mask:0xf\n\t"  // 15
      "v_fmac_f32_dpp %[a4], %[h], %[w14] row_ror:14 row_mask:0xf bank_mask:0xf\n\t"  // 16
      "v_fmac_f32_dpp %[a0], %[h], %[w15] row_ror:15 row_mask:0xf bank_mask:0xf\n\t"  // 17 (a0: 12->17)
      "v_add_f32 %[a1], %[a1], %[a2]\n\t"              // 18: a1(13)+a2(14)
      "v_add_f32 %[a3], %[a3], %[a4]\n\t"              // 19: a3(15)+a4(16)
      "v_add_f32 %[a1], %[a1], %[a3]\n\t"              // 20: a1(18)+a3(19)
      "v_add_f32 %[a0], %[a0], %[a1]\n\t"              // 21: a0(17)+a1(20)
      "v_max_f32 %[h], 0, %[a0]"                       // 22: relu
      : [xon] "=&v"(xon), [a0] "=&v"(a0), [a1] "=&v"(a1), [a2] "=&v"(a2),
        [a3] "=&v"(a3), [a4] "=&v"(a4), [h] "+v"(h)
      : [xi] "v"(xi), [xsn] "v"(xsn), [wih] "v"(wih), [bs] "v"(bias),
        [w0] "v"(w[0]),  [w1] "v"(w[1]),  [w2] "v"(w[2]),  [w3] "v"(w[3]),
        [w4] "v"(w[4]),  [w5] "v"(w[5]),  [w6] "v"(w[6]),  [w7] "v"(w[7]),
        [w8] "v"(w[8]),  [w9] "v"(w[9]),  [w10] "v"(w[10]), [w11] "v"(w[11]),
        [w12] "v"(w[12]), [w13] "v"(w[13]), [w14] "v"(w[14]), [w15] "v"(w[15]));
  xi = xon;
}

// Each step consumes xi_t (carried) and feeds x_{t+1} to the head-filler.
#define S1(XN) step(h, xi, (XN), w, wih, bias);
#define HALF_A                                                              \
  S1(A0.y) S1(A0.z) S1(A0.w) S1(A1.x) S1(A1.y) S1(A1.z) S1(A1.w) S1(A2.x)  \
  S1(A2.y) S1(A2.z) S1(A2.w) S1(A3.x) S1(A3.y) S1(A3.z) S1(A3.w) S1(B0.x)
#define HALF_B                                                              \
  S1(B0.y) S1(B0.z) S1(B0.w) S1(B1.x) S1(B1.y) S1(B1.z) S1(B1.w) S1(B2.x)  \
  S1(B2.y) S1(B2.z) S1(B2.w) S1(B3.x) S1(B3.y) S1(B3.z) S1(B3.w) S1(A0.x)

// --- kernel ------------------------------------------------------------------
__global__ __launch_bounds__(256) void rnn_relu_kernel(
    const float* __restrict__ x, const float* __restrict__ W_ih,
    const float* __restrict__ b_ih, const float* __restrict__ W_hh,
    const float* __restrict__ b_hh, const float* __restrict__ W_fc,
    const float* __restrict__ b_fc, float* __restrict__ out) {
  const int tid = threadIdx.x;
  const int j   = tid & 15;                        // h index owned by this lane
  const int b   = blockIdx.x * 16 + (tid >> 4);    // batch per 16-lane row

  // Probe row_ror:1 direction (ctrl 0x121 == asm row_ror:1), R1/R2-proven.
  int pr = __builtin_amdgcn_update_dpp(0, j, 0x121, 0xF, 0xF, true);
  const bool plus = (pr == ((j + 1) & 15));

  // w[s] = W_hh[j][sigma_s(j)] so ror_s(h)*w[s] contributes W_hh[j,k]*h[k].
  float w[16];
#pragma unroll
  for (int s = 0; s < 16; ++s) {
    int k = (j + (plus ? s : (16 - s))) & 15;
    w[s] = W_hh[j * 16 + k];
  }
  const float wih  = W_ih[j];
  const float bias = b_ih[j] + b_hh[j];

  // R6-proven load pipeline: A/B double-buffered f4 quads, loads issued a
  // full 16 steps before first use; no copies, no branch in body.
  const f4* __restrict__ xr = (const f4*)(x + (size_t)b * T_LEN);

  float h = 0.0f;
  f4 A0 = xr[0], A1 = xr[1], A2 = xr[2], A3 = xr[3];
  f4 B0, B1, B2, B3;
  float xi = fmaf(A0.x, wih, bias);        // xi for step 0
  const f4* p = xr + 4;                    // chunk t0+16 (B source)

#pragma unroll 1
  for (int t0 = 0; t0 < T_LEN; t0 += 32) {
    B0 = p[0]; B1 = p[1]; B2 = p[2]; B3 = p[3];     // load chunk t0+16
    HALF_A                                           // steps t0 .. t0+15
    const f4* pa = (t0 + 32 < T_LEN) ? (p + 4) : xr; // wrap on final iter
    A0 = pa[0]; A1 = pa[1]; A2 = pa[2]; A3 = pa[3];  // load chunk t0+32
    HALF_B                                           // steps t0+16 .. t0+31
    p += 8;
  }
  // (final step's xi-prefetch reads wrapped x[0] -- value discarded)

  // Epilogue: out[b, c] = sum_j h[j] * W_fc[c, j] + b_fc[c]  (R2-proven)
  float p0 = h * W_fc[j];
  float p1 = h * W_fc[16 + j];
  p0 += __int_as_float(__builtin_amdgcn_ds_swizzle(__float_as_int(p0), 0x041F));
  p1 += __int_as_float(__builtin_amdgcn_ds_swizzle(__float_as_int(p1), 0x041F));
  p0 += __int_as_float(__builtin_amdgcn_ds_swizzle(__float_as_int(p0), 0x081F));
  p1 += __int_as_float(__builtin_amdgcn_ds_swizzle(__float_as_int(p1), 0x081F));
  p0 += __int_as_float(__builtin_amdgcn_ds_swizzle(__float_as_int(p0), 0x101F));
  p1 += __int_as_float(__builtin_amdgcn_ds_swizzle(__float_as_int(p1), 0x101F));
  p0 += __int_as_float(__builtin_amdgcn_ds_swizzle(__float_as_int(p0), 0x201F));
  p1 += __int_as_float(__builtin_amdgcn_ds_swizzle(__float_as_int(p1), 0x201F));

  if (j == 0) {
    out[b * 2 + 0] = p0 + b_fc[0];
    out[b * 2 + 1] = p1 + b_fc[1];
  }
}

// --- launch ------------------------------------------------------------------
extern "C" void kernel_launch(void* const* d_in, const int* in_sizes, int n_in,
                              void* d_out, int out_size, void* d_ws, size_t ws_size,
                              hipStream_t stream) {
  const float* x    = (const float*)d_in[0];
  const float* W_ih = (const float*)d_in[1];
  const float* b_ih = (const float*)d_in[2];
  const float* W_hh = (const float*)d_in[3];
  const float* b_hh = (const float*)d_in[4];
  const float* W_fc = (const float*)d_in[5];
  const float* b_fc = (const float*)d_in[6];
  float* out = (float*)d_out;

  const int B = 4096;
  dim3 grid(B / 16);   // 256 blocks: 4 batches/wave, 1024 waves = 1/SIMD
  dim3 block(256);
  hipLaunchKernelGGL(rnn_relu_kernel, grid, block, 0, stream,
                     x, W_ih, b_ih, W_hh, b_hh, W_fc, b_fc, out);
}

// Round 11
// 91.781 us; speedup vs baseline: 2.3450x; 1.0819x over previous
//
#include <hip/hip_runtime.h>

#define T_LEN 2048

typedef float f4 __attribute__((ext_vector_type(4)));

// --- one timestep (R2/R6-proven block; best measured: 92.2 us) ---------------
// h_new[j] = relu( x_t*wih[j] + bias[j] + sum_k W_hh[j,k]*h[k] )
// 15 fused DPP rotations (irreducible cross-lane count for full-rank 16x16
// matvec at 1 elem/lane), 4 independent accumulator chains. DPP hazard
// (VALU write -> DPP read needs 2 wait states) satisfied: first two
// instructions don't DPP-read h.
// Fitted costs (R6/R8/R10): DPP ~6.6 cyc, plain ~2 cyc -> floor ~111 cyc/step;
// this kernel measures 108. Compute-bound at the DPP-crossbar issue rate.
__device__ __forceinline__ void step(float& h, float xs, const float (&w)[16],
                                     float wih, float bias) {
  float a0, a1, a2, a3;
  asm("v_fma_f32 %0, %5, %6, %7\n\t"
      "v_fmac_f32 %0, %4, %8\n\t"
      "v_mul_f32_dpp %1, %4, %9  row_ror:1  row_mask:0xf bank_mask:0xf\n\t"
      "v_mul_f32_dpp %2, %4, %10 row_ror:2  row_mask:0xf bank_mask:0xf\n\t"
      "v_mul_f32_dpp %3, %4, %11 row_ror:3  row_mask:0xf bank_mask:0xf\n\t"
      "v_fmac_f32_dpp %0, %4, %12 row_ror:4  row_mask:0xf bank_mask:0xf\n\t"
      "v_fmac_f32_dpp %1, %4, %13 row_ror:5  row_mask:0xf bank_mask:0xf\n\t"
      "v_fmac_f32_dpp %2, %4, %14 row_ror:6  row_mask:0xf bank_mask:0xf\n\t"
      "v_fmac_f32_dpp %3, %4, %15 row_ror:7  row_mask:0xf bank_mask:0xf\n\t"
      "v_fmac_f32_dpp %0, %4, %16 row_ror:8  row_mask:0xf bank_mask:0xf\n\t"
      "v_fmac_f32_dpp %1, %4, %17 row_ror:9  row_mask:0xf bank_mask:0xf\n\t"
      "v_fmac_f32_dpp %2, %4, %18 row_ror:10 row_mask:0xf bank_mask:0xf\n\t"
      "v_fmac_f32_dpp %3, %4, %19 row_ror:11 row_mask:0xf bank_mask:0xf\n\t"
      "v_fmac_f32_dpp %0, %4, %20 row_ror:12 row_mask:0xf bank_mask:0xf\n\t"
      "v_fmac_f32_dpp %1, %4, %21 row_ror:13 row_mask:0xf bank_mask:0xf\n\t"
      "v_fmac_f32_dpp %2, %4, %22 row_ror:14 row_mask:0xf bank_mask:0xf\n\t"
      "v_fmac_f32_dpp %3, %4, %23 row_ror:15 row_mask:0xf bank_mask:0xf\n\t"
      "v_add_f32 %0, %0, %1\n\t"
      "v_add_f32 %2, %2, %3\n\t"
      "v_add_f32 %0, %0, %2\n\t"
      "v_max_f32 %4, 0, %0"
      : "=&v"(a0), "=&v"(a1), "=&v"(a2), "=&v"(a3), "+v"(h)
      : "v"(xs), "v"(wih), "v"(bias),
        "v"(w[0]), "v"(w[1]), "v"(w[2]), "v"(w[3]),
        "v"(w[4]), "v"(w[5]), "v"(w[6]), "v"(w[7]),
        "v"(w[8]), "v"(w[9]), "v"(w[10]), "v"(w[11]),
        "v"(w[12]), "v"(w[13]), "v"(w[14]), "v"(w[15]));
}

#define STEP16(C0, C1, C2, C3)            \
  do {                                    \
    step(h, (C0).x, w, wih, bias);        \
    step(h, (C0).y, w, wih, bias);        \
    step(h, (C0).z, w, wih, bias);        \
    step(h, (C0).w, w, wih, bias);        \
    step(h, (C1).x, w, wih, bias);        \
    step(h, (C1).y, w, wih, bias);        \
    step(h, (C1).z, w, wih, bias);        \
    step(h, (C1).w, w, wih, bias);        \
    step(h, (C2).x, w, wih, bias);        \
    step(h, (C2).y, w, wih, bias);        \
    step(h, (C2).z, w, wih, bias);        \
    step(h, (C2).w, w, wih, bias);        \
    step(h, (C3).x, w, wih, bias);        \
    step(h, (C3).y, w, wih, bias);        \
    step(h, (C3).z, w, wih, bias);        \
    step(h, (C3).w, w, wih, bias);        \
  } while (0)

// --- kernel -----------------------------------------------------------------
__global__ __launch_bounds__(256) void rnn_relu_kernel(
    const float* __restrict__ x, const float* __restrict__ W_ih,
    const float* __restrict__ b_ih, const float* __restrict__ W_hh,
    const float* __restrict__ b_hh, const float* __restrict__ W_fc,
    const float* __restrict__ b_fc, float* __restrict__ out) {
  const int tid = threadIdx.x;
  const int j   = tid & 15;                        // h index owned by this lane
  const int b   = blockIdx.x * 16 + (tid >> 4);    // batch per 16-lane row

  // Probe row_ror:1 direction (ctrl 0x121 == asm row_ror:1), R1/R2-proven.
  int pr = __builtin_amdgcn_update_dpp(0, j, 0x121, 0xF, 0xF, true);
  const bool plus = (pr == ((j + 1) & 15));

  // w[s] = W_hh[j][sigma_s(j)] so ror_s(h)*w[s] contributes W_hh[j,k]*h[k].
  float w[16];
#pragma unroll
  for (int s = 0; s < 16; ++s) {
    int k = (j + (plus ? s : (16 - s))) & 15;
    w[s] = W_hh[j * 16 + k];
  }
  const float wih  = W_ih[j];
  const float bias = b_ih[j] + b_hh[j];

  // R6-proven load pipeline: A/B double-buffered f4 quads, loads issued a
  // full 16 steps (~1000+ cyc) before first use; no copies, no branch in body.
  const f4* __restrict__ xr = (const f4*)(x + (size_t)b * T_LEN);

  float h = 0.0f;
  f4 A0 = xr[0], A1 = xr[1], A2 = xr[2], A3 = xr[3];
  f4 B0, B1, B2, B3;
  const f4* p = xr + 4;                    // chunk t0+16 (B buffer source)

#pragma unroll 1
  for (int t0 = 0; t0 < T_LEN; t0 += 32) {
    B0 = p[0]; B1 = p[1]; B2 = p[2]; B3 = p[3];     // load chunk t0+16
    STEP16(A0, A1, A2, A3);                          // steps t0 .. t0+15
    const f4* pa = (t0 + 32 < T_LEN) ? (p + 4) : xr; // wrap on final iter
    A0 = pa[0]; A1 = pa[1]; A2 = pa[2]; A3 = pa[3];  // load chunk t0+32
    STEP16(B0, B1, B2, B3);                          // steps t0+16 .. t0+31
    p += 8;
  }

  // Epilogue: out[b, c] = sum_j h[j] * W_fc[c, j] + b_fc[c]  (R2-proven)
  float p0 = h * W_fc[j];
  float p1 = h * W_fc[16 + j];
  p0 += __int_as_float(__builtin_amdgcn_ds_swizzle(__float_as_int(p0), 0x041F));
  p1 += __int_as_float(__builtin_amdgcn_ds_swizzle(__float_as_int(p1), 0x041F));
  p0 += __int_as_float(__builtin_amdgcn_ds_swizzle(__float_as_int(p0), 0x081F));
  p1 += __int_as_float(__builtin_amdgcn_ds_swizzle(__float_as_int(p1), 0x081F));
  p0 += __int_as_float(__builtin_amdgcn_ds_swizzle(__float_as_int(p0), 0x101F));
  p1 += __int_as_float(__builtin_amdgcn_ds_swizzle(__float_as_int(p1), 0x101F));
  p0 += __int_as_float(__builtin_amdgcn_ds_swizzle(__float_as_int(p0), 0x201F));
  p1 += __int_as_float(__builtin_amdgcn_ds_swizzle(__float_as_int(p1), 0x201F));

  if (j == 0) {
    out[b * 2 + 0] = p0 + b_fc[0];
    out[b * 2 + 1] = p1 + b_fc[1];
  }
}

// --- launch -----------------------------------------------------------------
extern "C" void kernel_launch(void* const* d_in, const int* in_sizes, int n_in,
                              void* d_out, int out_size, void* d_ws, size_t ws_size,
                              hipStream_t stream) {
  const float* x    = (const float*)d_in[0];
  const float* W_ih = (const float*)d_in[1];
  const float* b_ih = (const float*)d_in[2];
  const float* W_hh = (const float*)d_in[3];
  const float* b_hh = (const float*)d_in[4];
  const float* W_fc = (const float*)d_in[5];
  const float* b_fc = (const float*)d_in[6];
  float* out = (float*)d_out;

  const int B = 4096;
  dim3 grid(B / 16);   // 256 blocks: 4 batches per wave, 1024 waves = 1/SIMD
  dim3 block(256);
  hipLaunchKernelGGL(rnn_relu_kernel, grid, block, 0, stream,
                     x, W_ih, b_ih, W_hh, b_hh, W_fc, b_fc, out);
}